// Round 13
// baseline (174.971 us; speedup 1.0000x reference)
//
#include <hip/hip_runtime.h>
#include <hip/hip_bf16.h>
#include <math.h>

#define N_NODES 60000
#define IN_CH   128
#define HID     32
#define N_EDGES 600000
#define CAP     32

// workspace layout in 4-byte units
#define WS_CNT    0           // 60000 ints
#define WS_SUM    60000       // 1 float
#define WS_BUCKET 60008       // 60000*32 u16 (3.84 MB)
#define WS_HS     2940032     // 60000*128 bf16 (UNSCALED h) -- 15.4 MB
#define WS_X      10620032    // 60000*64 uints (bf16x2 x)   -- 15.4 MB

#define GEMM_BLOCKS 469       // 469 * 128 rows >= 60000 (2 strips of 64)
#define HIST_BLOCKS 2344      // 2344 * 256 edges >= 600000

typedef float  v4f __attribute__((ext_vector_type(4)));
typedef short  v8s __attribute__((ext_vector_type(8)));

static __device__ inline short f2bf(float f) {
    __hip_bfloat16 h = __float2bfloat16(f);   // RNE
    union { __hip_bfloat16 h; short s; } u; u.h = h; return u.s;
}
static __device__ inline float bf2f(short s) {
    return __uint_as_float(((unsigned int)(unsigned short)s) << 16);
}
static __device__ inline float bflo(unsigned int u) { return __uint_as_float(u << 16); }
static __device__ inline float bfhi(unsigned int u) { return __uint_as_float(u & 0xffff0000u); }
static __device__ inline int   rdl_i(int v, int l)   { return __builtin_amdgcn_readlane(v, l); }
static __device__ inline float rdl_f(float v, int l) {
    return __int_as_float(__builtin_amdgcn_readlane(__float_as_int(v), l));
}

// K1 (fat): hist role + gemm role in one launch.
// hist:  1 edge/thread, max TLP (proven). cnt[d]=deg; bucket16[d*CAP+slot]=src.
// gemm:  hs = bf16(state @ Wg), 128 rows/block (2 strips over ONE Wg staging --
//        the isolated delta: halves per-block staging overhead vs R10's 64 rows).
// Role split 1:5 by blockIdx%6.
__launch_bounds__(256)
__global__ void k_fat(const float* __restrict__ state, const float* __restrict__ Wg,
                      const int* __restrict__ eidx, int* __restrict__ cnt,
                      unsigned short* __restrict__ bucket, unsigned short* __restrict__ hs) {
    __shared__ __align__(16) short Bs[128 * 136];   // 34.8 KB (gemm role only)
    const int bid = blockIdx.x;
    const int r6 = bid % 6, q6 = bid / 6;
    const int t = threadIdx.x;

    if (r6 >= 1) {
        // ---- hist role: 2344 blocks x 256 edges, 1 edge/thread ----
        const int hb = q6 * 5 + (r6 - 1);
        const int i = hb * 256 + t;
        if (i < N_EDGES) {
            int s = eidx[i];
            int d = eidx[N_EDGES + i];
            int slot = atomicAdd(&cnt[d], 1);
            if (slot < CAP) bucket[d * CAP + slot] = (unsigned short)s;
        }
        return;
    }

    // ---- gemm role: 469 blocks x 128 rows (2 strips of 64) ----
    const int gb = q6;

    // stage Wg -> Bs[n][k] (bf16, transposed) -- once per 128 rows
    for (int idx = t; idx < 128 * 128; idx += 256) {
        int k = idx >> 7, n = idx & 127;
        Bs[n * 136 + k] = f2bf(Wg[idx]);
    }
    __syncthreads();

    const int w = t >> 6, lane = t & 63;
    const int quad = lane >> 4, m = lane & 15;

#pragma unroll 1
    for (int strip = 0; strip < 2; ++strip) {
        const int rowBase = gb * 128 + strip * 64;
        int arow = rowBase + w * 16 + m;
        if (arow > N_NODES - 1) arow = N_NODES - 1;

        v8s a[4];
        const float4* sp = (const float4*)(state + (size_t)arow * 128);
#pragma unroll
        for (int q = 0; q < 4; ++q) {
            float4 v0 = sp[q * 8 + quad * 2];
            float4 v1 = sp[q * 8 + quad * 2 + 1];
            v8s af;
            af[0] = f2bf(v0.x); af[1] = f2bf(v0.y); af[2] = f2bf(v0.z); af[3] = f2bf(v0.w);
            af[4] = f2bf(v1.x); af[5] = f2bf(v1.y); af[6] = f2bf(v1.z); af[7] = f2bf(v1.w);
            a[q] = af;
        }

        v4f acc[8];
#pragma unroll
        for (int tt = 0; tt < 8; ++tt) acc[tt] = (v4f)0.f;

#pragma unroll
        for (int tt = 0; tt < 8; ++tt) {
            const short* bp = &Bs[(tt * 16 + m) * 136];
#pragma unroll
            for (int q = 0; q < 4; ++q) {
                v8s b = *(const v8s*)(bp + q * 32 + quad * 8);
                acc[tt] = __builtin_amdgcn_mfma_f32_16x16x32_bf16(a[q], b, acc[tt], 0, 0, 0);
            }
        }

        // epilogue: row = rowBase + w*16 + quad*4 + r, col = tt*16 + m
#pragma unroll
        for (int tt = 0; tt < 8; ++tt) {
#pragma unroll
            for (int r = 0; r < 4; ++r) {
                int rr = rowBase + w * 16 + quad * 4 + r;
                if (rr < N_NODES)
                    hs[(size_t)rr * 128 + tt * 16 + m] = (unsigned short)f2bf(acc[tt][r]);
            }
        }
    }
}

// K2: gather, two interleaved rows per wave (R12, measured-neutral-kept:
// halves bucket-line reads). Lanes 0-31 = row0 slots, 32-63 = row1 slots.
__launch_bounds__(256)
__global__ void k_gather(const unsigned short* __restrict__ hs, const float* __restrict__ state,
                         const int* __restrict__ cnt, const unsigned short* __restrict__ bucket,
                         const float* __restrict__ bg, unsigned int* __restrict__ xb) {
    const int wave = threadIdx.x >> 6, lane = threadIdx.x & 63;
    const int row0 = blockIdx.x * 8 + wave * 2;
    if (row0 >= N_NODES) return;
    const int row1 = row0 + 1;   // N_NODES even: always valid

    const int ci0 = cnt[row0];
    const int ci1 = cnt[row1];
    int sl = (int)bucket[(size_t)row0 * CAP + lane];   // both rows' slots
    const unsigned int* hp = (const unsigned int*)hs;  // bf16x2 per dword
    unsigned int us0 = hp[(unsigned)row0 * 64u + lane];
    unsigned int us1 = hp[(unsigned)row1 * 64u + lane];
    float2 bgv = ((const float2*)bg)[lane];
    float2 st0 = ((const float2*)state)[(unsigned)row0 * 64u + lane];
    float2 st1 = ((const float2*)state)[(unsigned)row1 * 64u + lane];

    const float dinv0 = rsqrtf((float)ci0 + 1.0f);
    const float dinv1 = rsqrtf((float)ci1 + 1.0f);
    const int nb0 = ci0 < CAP ? ci0 : CAP;
    const int nb1 = ci1 < CAP ? ci1 : CAP;

    const bool valid = (lane < 32) ? (lane < nb0) : ((lane - 32) < nb1);
    int slot = 0; float dvv = 0.f;
    if (valid) {
        slot = sl;
        dvv = rsqrtf((float)cnt[slot] + 1.0f);
    }

    float ax0 = bflo(us0) * dinv0, ay0 = bfhi(us0) * dinv0;   // self terms
    float ax1 = bflo(us1) * dinv1, ay1 = bfhi(us1) * dinv1;

    const int nmax = nb0 > nb1 ? nb0 : nb1;
    for (int s = 0; s < nmax; s += 4) {
        int   a0 = rdl_i(slot, s + 0), a1 = rdl_i(slot, s + 1);
        int   a2 = rdl_i(slot, s + 2), a3 = rdl_i(slot, s + 3);
        int   b0 = rdl_i(slot, 32 + s + 0), b1 = rdl_i(slot, 32 + s + 1);
        int   b2 = rdl_i(slot, 32 + s + 2), b3 = rdl_i(slot, 32 + s + 3);
        float e0 = rdl_f(dvv, s + 0), e1 = rdl_f(dvv, s + 1);
        float e2 = rdl_f(dvv, s + 2), e3 = rdl_f(dvv, s + 3);
        float f0 = rdl_f(dvv, 32 + s + 0), f1 = rdl_f(dvv, 32 + s + 1);
        float f2 = rdl_f(dvv, 32 + s + 2), f3 = rdl_f(dvv, 32 + s + 3);
        unsigned int ua0 = hp[(unsigned)a0 * 64u + lane];
        unsigned int ua1 = hp[(unsigned)a1 * 64u + lane];
        unsigned int ua2 = hp[(unsigned)a2 * 64u + lane];
        unsigned int ua3 = hp[(unsigned)a3 * 64u + lane];
        unsigned int ub0 = hp[(unsigned)b0 * 64u + lane];
        unsigned int ub1 = hp[(unsigned)b1 * 64u + lane];
        unsigned int ub2 = hp[(unsigned)b2 * 64u + lane];
        unsigned int ub3 = hp[(unsigned)b3 * 64u + lane];
        ax0 = fmaf(e0, bflo(ua0), ax0); ay0 = fmaf(e0, bfhi(ua0), ay0);
        ax0 = fmaf(e1, bflo(ua1), ax0); ay0 = fmaf(e1, bfhi(ua1), ay0);
        ax0 = fmaf(e2, bflo(ua2), ax0); ay0 = fmaf(e2, bfhi(ua2), ay0);
        ax0 = fmaf(e3, bflo(ua3), ax0); ay0 = fmaf(e3, bfhi(ua3), ay0);
        ax1 = fmaf(f0, bflo(ub0), ax1); ay1 = fmaf(f0, bfhi(ub0), ay1);
        ax1 = fmaf(f1, bflo(ub1), ax1); ay1 = fmaf(f1, bfhi(ub1), ay1);
        ax1 = fmaf(f2, bflo(ub2), ax1); ay1 = fmaf(f2, bfhi(ub2), ay1);
        ax1 = fmaf(f3, bflo(ub3), ax1); ay1 = fmaf(f3, bfhi(ub3), ay1);
    }
    float ox0 = fmaxf(fmaf(dinv0, ax0, bgv.x), 0.f) + st0.x;
    float oy0 = fmaxf(fmaf(dinv0, ay0, bgv.y), 0.f) + st0.y;
    float ox1 = fmaxf(fmaf(dinv1, ax1, bgv.x), 0.f) + st1.x;
    float oy1 = fmaxf(fmaf(dinv1, ay1, bgv.y), 0.f) + st1.y;
    unsigned int p0 = ((unsigned int)(unsigned short)f2bf(oy0) << 16)
                    | ((unsigned int)(unsigned short)f2bf(ox0));
    unsigned int p1 = ((unsigned int)(unsigned short)f2bf(oy1) << 16)
                    | ((unsigned int)(unsigned short)f2bf(ox1));
    xb[(unsigned)row0 * 64u + lane] = p0;
    xb[(unsigned)row1 * 64u + lane] = p1;
}

// K3: MFMA MLP (R10 proven version).
__launch_bounds__(256)
__global__ void k_mlp(const unsigned int* __restrict__ xb,
                      const float* __restrict__ W1, const float* __restrict__ b1,
                      const float* __restrict__ W2, const float* __restrict__ b2,
                      const float* __restrict__ W3, const float* __restrict__ b3,
                      float* __restrict__ out, float* __restrict__ sum) {
    __shared__ __align__(16) short BsH[32 * 136];   // W1^T hi
    __shared__ __align__(16) short BsL[32 * 136];   // W1^T lo
    __shared__ float  zs[4][16 * 33];
    __shared__ float4 W2s[32 * 8];
    __shared__ float  b1s[32], b2s[32], W3s[32];
    __shared__ float  wred[4];
    const int t = threadIdx.x;

    for (int idx = t; idx < 128 * 32; idx += 256) {
        int k = idx >> 5, j = idx & 31;
        float f = W1[idx];
        short hi = f2bf(f);
        short lo = f2bf(f - bf2f(hi));
        BsH[j * 136 + k] = hi;
        BsL[j * 136 + k] = lo;
    }
    W2s[t] = ((const float4*)W2)[t];
    if (t < 32) { b1s[t] = b1[t]; b2s[t] = b2[t]; W3s[t] = W3[t]; }
    __syncthreads();

    const int wv = t >> 6, lane = t & 63;
    const int quad = lane >> 4, m = lane & 15;
    const int rbase = (blockIdx.x * 4 + wv) * 16;
    float wavesum = 0.f;

    if (rbase < N_NODES) {
        v8s a[4];
        const int4* xp = (const int4*)(xb + (size_t)(rbase + m) * 64);
#pragma unroll
        for (int q = 0; q < 4; ++q) a[q] = *(const v8s*)&xp[q * 4 + quad];

        v4f acc0 = (v4f)0.f, acc1 = (v4f)0.f;
#pragma unroll
        for (int q = 0; q < 4; ++q) {
            v8s bh0 = *(const v8s*)&BsH[m * 136 + q * 32 + quad * 8];
            v8s bh1 = *(const v8s*)&BsH[(16 + m) * 136 + q * 32 + quad * 8];
            acc0 = __builtin_amdgcn_mfma_f32_16x16x32_bf16(a[q], bh0, acc0, 0, 0, 0);
            acc1 = __builtin_amdgcn_mfma_f32_16x16x32_bf16(a[q], bh1, acc1, 0, 0, 0);
        }
#pragma unroll
        for (int q = 0; q < 4; ++q) {
            v8s bl0 = *(const v8s*)&BsL[m * 136 + q * 32 + quad * 8];
            v8s bl1 = *(const v8s*)&BsL[(16 + m) * 136 + q * 32 + quad * 8];
            acc0 = __builtin_amdgcn_mfma_f32_16x16x32_bf16(a[q], bl0, acc0, 0, 0, 0);
            acc1 = __builtin_amdgcn_mfma_f32_16x16x32_bf16(a[q], bl1, acc1, 0, 0, 0);
        }

        float* zsw = zs[wv];
        float bj0 = b1s[m], bj1 = b1s[16 + m];
#pragma unroll
        for (int r = 0; r < 4; ++r) {
            float h0 = acc0[r] + bj0; h0 = h0 > 0.f ? h0 : 0.01f * h0;
            float h1 = acc1[r] + bj1; h1 = h1 > 0.f ? h1 : 0.01f * h1;
            zsw[(quad * 4 + r) * 33 + m]      = h0;
            zsw[(quad * 4 + r) * 33 + 16 + m] = h1;
        }
        asm volatile("s_waitcnt lgkmcnt(0)" ::: "memory");

        float h2[8];
#pragma unroll
        for (int j = 0; j < 8; ++j) h2[j] = b2s[quad * 8 + j];
        const float* zrow = &zsw[m * 33];
#pragma unroll
        for (int k = 0; k < 32; ++k) {
            float zk = zrow[k];
            float4 wA = W2s[k * 8 + quad * 2];
            float4 wB = W2s[k * 8 + quad * 2 + 1];
            h2[0] = fmaf(zk, wA.x, h2[0]); h2[1] = fmaf(zk, wA.y, h2[1]);
            h2[2] = fmaf(zk, wA.z, h2[2]); h2[3] = fmaf(zk, wA.w, h2[3]);
            h2[4] = fmaf(zk, wB.x, h2[4]); h2[5] = fmaf(zk, wB.y, h2[5]);
            h2[6] = fmaf(zk, wB.z, h2[6]); h2[7] = fmaf(zk, wB.w, h2[7]);
        }
        float a3p = 0.f;
#pragma unroll
        for (int j = 0; j < 8; ++j) {
            float z2 = h2[j] > 0.f ? h2[j] : 0.01f * h2[j];
            a3p = fmaf(z2, W3s[quad * 8 + j], a3p);
        }
        a3p += __shfl_xor(a3p, 16, 64);
        a3p += __shfl_xor(a3p, 32, 64);
        float a3 = a3p + b3[0];
        float sp = fmaxf(a3, 0.f) + log1pf(expf(-fabsf(a3)));  // stable softplus
        if (quad == 0) out[rbase + m] = sp;
        float p = (quad == 0) ? sp : 0.f;
#pragma unroll
        for (int off = 32; off >= 1; off >>= 1) p += __shfl_xor(p, off, 64);
        wavesum = p;
    }
    if (lane == 0) wred[wv] = wavesum;
    __syncthreads();
    if (t == 0) atomicAdd(sum, (wred[0] + wred[1]) + (wred[2] + wred[3]));
}

// K4: in-place action = conc / (sum + 1e-20), float4-vectorized
__global__ void k_norm(const float* __restrict__ sum, float* __restrict__ out) {
    int i = blockIdx.x * blockDim.x + threadIdx.x;
    if (i < N_NODES / 4) {
        float inv = 1.0f / (*sum + 1e-20f);
        float4* o4 = (float4*)out;
        float4 v = o4[i];
        v.x *= inv; v.y *= inv; v.z *= inv; v.w *= inv;
        o4[i] = v;
    }
}

extern "C" void kernel_launch(void* const* d_in, const int* in_sizes, int n_in,
                              void* d_out, int out_size, void* d_ws, size_t ws_size,
                              hipStream_t stream) {
    const float* state = (const float*)d_in[0];
    const float* Wg    = (const float*)d_in[1];
    const float* bg    = (const float*)d_in[2];
    const float* W1    = (const float*)d_in[3];
    const float* b1    = (const float*)d_in[4];
    const float* W2    = (const float*)d_in[5];
    const float* b2    = (const float*)d_in[6];
    const float* W3    = (const float*)d_in[7];
    const float* b3    = (const float*)d_in[8];
    const int*   eidx  = (const int*)d_in[9];
    float* out = (float*)d_out;

    int*   wi = (int*)d_ws;
    float* wf = (float*)d_ws;
    int*   cnt    = wi + WS_CNT;
    float* sum    = wf + WS_SUM;
    unsigned short* bucket = (unsigned short*)(wi + WS_BUCKET);
    unsigned short* hs = (unsigned short*)(wf + WS_HS);
    unsigned int*   xb = (unsigned int*)(wf + WS_X);

    hipMemsetAsync(cnt, 0, 60001 * sizeof(int), stream);  // cnt + sum

    // fat: 469 gemm blocks (r6==0) + 2344 hist blocks (r6>=1) = 2813
    k_fat<<<GEMM_BLOCKS + HIST_BLOCKS, 256, 0, stream>>>(state, Wg, eidx, cnt, bucket, hs);
    // gather: 2 rows/wave interleaved, 4 waves/block -> 7500 blocks
    k_gather<<<(N_NODES + 7) / 8, 256, 0, stream>>>(hs, state, cnt, bucket, bg, xb);
    // mlp: 16 rows/wave, 4 waves/block -> 938 blocks
    k_mlp<<<938, 256, 0, stream>>>(xb, W1, b1, W2, b2, W3, b3, out, sum);
    k_norm<<<(N_NODES / 4 + 255) / 256, 256, 0, stream>>>(sum, out);
}

// Round 14
// 169.369 us; speedup vs baseline: 1.0331x; 1.0331x over previous
//
#include <hip/hip_runtime.h>
#include <hip/hip_bf16.h>
#include <math.h>

#define N_NODES 60000
#define IN_CH   128
#define HID     32
#define N_EDGES 600000
#define CAP     32

// workspace layout in 4-byte units
#define WS_CNT    0           // 60000 ints
#define WS_SUM    60000       // 1 float
#define WS_BUCKET 60008       // 60000*32 u16 (3.84 MB)
#define WS_HS     2940032     // 60000*128 bf16 (UNSCALED h) -- 15.4 MB
#define WS_X      10620032    // 60000*64 uints (bf16x2 x)   -- 15.4 MB

typedef float  v4f __attribute__((ext_vector_type(4)));
typedef short  v8s __attribute__((ext_vector_type(8)));

static __device__ inline short f2bf(float f) {
    __hip_bfloat16 h = __float2bfloat16(f);   // RNE
    union { __hip_bfloat16 h; short s; } u; u.h = h; return u.s;
}
static __device__ inline float bf2f(short s) {
    return __uint_as_float(((unsigned int)(unsigned short)s) << 16);
}
static __device__ inline float bflo(unsigned int u) { return __uint_as_float(u << 16); }
static __device__ inline float bfhi(unsigned int u) { return __uint_as_float(u & 0xffff0000u); }
static __device__ inline int   rdl_i(int v, int l)   { return __builtin_amdgcn_readlane(v, l); }
static __device__ inline float rdl_f(float v, int l) {
    return __int_as_float(__builtin_amdgcn_readlane(__float_as_int(v), l));
}

// K1 (fat): hist role + gemm role in one launch (R10/R12 measured-best version).
// hist:  1 edge/thread, max TLP. cnt[d]=deg; bucket16[d*CAP+slot]=(u16)src.
// gemm:  hs = bf16(state @ Wg), 64 rows/block, VGPR 52 (do NOT strip-amortize:
//        R2 and R13 both showed VGPR 100 / occupancy 12% regressions).
// Role split 2:5 by blockIdx%7.
__launch_bounds__(256)
__global__ void k_fat(const float* __restrict__ state, const float* __restrict__ Wg,
                      const int* __restrict__ eidx, int* __restrict__ cnt,
                      unsigned short* __restrict__ bucket, unsigned short* __restrict__ hs) {
    __shared__ __align__(16) short Bs[128 * 136];   // 34.8 KB (gemm role only)
    const int bid = blockIdx.x;
    const int r7 = bid % 7, q7 = bid / 7;
    const int t = threadIdx.x;

    if (r7 >= 2) {
        // ---- hist role: 2344 blocks x 256 edges, 1 edge/thread (max TLP) ----
        const int hb = q7 * 5 + (r7 - 2);
        const int i = hb * 256 + t;
        if (i < N_EDGES) {
            int s = eidx[i];
            int d = eidx[N_EDGES + i];
            int slot = atomicAdd(&cnt[d], 1);
            if (slot < CAP) bucket[d * CAP + slot] = (unsigned short)s;
        }
        return;
    }

    // ---- gemm role: 938 blocks x 64 rows ----
    const int gb = q7 * 2 + r7;

    for (int idx = t; idx < 128 * 128; idx += 256) {
        int k = idx >> 7, n = idx & 127;
        Bs[n * 136 + k] = f2bf(Wg[idx]);
    }
    __syncthreads();

    const int w = t >> 6, lane = t & 63;
    const int quad = lane >> 4, m = lane & 15;
    const int rowBase = gb * 64;
    int arow = rowBase + w * 16 + m;
    if (arow > N_NODES - 1) arow = N_NODES - 1;

    v8s a[4];
    const float4* sp = (const float4*)(state + (size_t)arow * 128);
#pragma unroll
    for (int q = 0; q < 4; ++q) {
        float4 v0 = sp[q * 8 + quad * 2];
        float4 v1 = sp[q * 8 + quad * 2 + 1];
        v8s af;
        af[0] = f2bf(v0.x); af[1] = f2bf(v0.y); af[2] = f2bf(v0.z); af[3] = f2bf(v0.w);
        af[4] = f2bf(v1.x); af[5] = f2bf(v1.y); af[6] = f2bf(v1.z); af[7] = f2bf(v1.w);
        a[q] = af;
    }

    v4f acc[8];
#pragma unroll
    for (int tt = 0; tt < 8; ++tt) acc[tt] = (v4f)0.f;

#pragma unroll
    for (int tt = 0; tt < 8; ++tt) {
        const short* bp = &Bs[(tt * 16 + m) * 136];
#pragma unroll
        for (int q = 0; q < 4; ++q) {
            v8s b = *(const v8s*)(bp + q * 32 + quad * 8);
            acc[tt] = __builtin_amdgcn_mfma_f32_16x16x32_bf16(a[q], b, acc[tt], 0, 0, 0);
        }
    }

#pragma unroll
    for (int tt = 0; tt < 8; ++tt) {
#pragma unroll
        for (int r = 0; r < 4; ++r) {
            int rr = rowBase + w * 16 + quad * 4 + r;
            if (rr < N_NODES)
                hs[(size_t)rr * 128 + tt * 16 + m] = (unsigned short)f2bf(acc[tt][r]);
        }
    }
}

// K2: gather, two interleaved rows per wave. Lanes 0-31 = row0 slots,
// 32-63 = row1 slots (one coalesced 128B u16 bucket read covers both rows).
__launch_bounds__(256)
__global__ void k_gather(const unsigned short* __restrict__ hs, const float* __restrict__ state,
                         const int* __restrict__ cnt, const unsigned short* __restrict__ bucket,
                         const float* __restrict__ bg, unsigned int* __restrict__ xb) {
    const int wave = threadIdx.x >> 6, lane = threadIdx.x & 63;
    const int row0 = blockIdx.x * 8 + wave * 2;
    if (row0 >= N_NODES) return;
    const int row1 = row0 + 1;   // N_NODES even: always valid

    const int ci0 = cnt[row0];
    const int ci1 = cnt[row1];
    int sl = (int)bucket[(size_t)row0 * CAP + lane];   // both rows' slots
    const unsigned int* hp = (const unsigned int*)hs;  // bf16x2 per dword
    unsigned int us0 = hp[(unsigned)row0 * 64u + lane];
    unsigned int us1 = hp[(unsigned)row1 * 64u + lane];
    float2 bgv = ((const float2*)bg)[lane];
    float2 st0 = ((const float2*)state)[(unsigned)row0 * 64u + lane];
    float2 st1 = ((const float2*)state)[(unsigned)row1 * 64u + lane];

    const float dinv0 = rsqrtf((float)ci0 + 1.0f);
    const float dinv1 = rsqrtf((float)ci1 + 1.0f);
    const int nb0 = ci0 < CAP ? ci0 : CAP;
    const int nb1 = ci1 < CAP ? ci1 : CAP;

    const bool valid = (lane < 32) ? (lane < nb0) : ((lane - 32) < nb1);
    int slot = 0; float dvv = 0.f;
    if (valid) {
        slot = sl;
        dvv = rsqrtf((float)cnt[slot] + 1.0f);
    }

    float ax0 = bflo(us0) * dinv0, ay0 = bfhi(us0) * dinv0;   // self terms
    float ax1 = bflo(us1) * dinv1, ay1 = bfhi(us1) * dinv1;

    const int nmax = nb0 > nb1 ? nb0 : nb1;
    for (int s = 0; s < nmax; s += 4) {
        int   a0 = rdl_i(slot, s + 0), a1 = rdl_i(slot, s + 1);
        int   a2 = rdl_i(slot, s + 2), a3 = rdl_i(slot, s + 3);
        int   b0 = rdl_i(slot, 32 + s + 0), b1 = rdl_i(slot, 32 + s + 1);
        int   b2 = rdl_i(slot, 32 + s + 2), b3 = rdl_i(slot, 32 + s + 3);
        float e0 = rdl_f(dvv, s + 0), e1 = rdl_f(dvv, s + 1);
        float e2 = rdl_f(dvv, s + 2), e3 = rdl_f(dvv, s + 3);
        float f0 = rdl_f(dvv, 32 + s + 0), f1 = rdl_f(dvv, 32 + s + 1);
        float f2 = rdl_f(dvv, 32 + s + 2), f3 = rdl_f(dvv, 32 + s + 3);
        unsigned int ua0 = hp[(unsigned)a0 * 64u + lane];
        unsigned int ua1 = hp[(unsigned)a1 * 64u + lane];
        unsigned int ua2 = hp[(unsigned)a2 * 64u + lane];
        unsigned int ua3 = hp[(unsigned)a3 * 64u + lane];
        unsigned int ub0 = hp[(unsigned)b0 * 64u + lane];
        unsigned int ub1 = hp[(unsigned)b1 * 64u + lane];
        unsigned int ub2 = hp[(unsigned)b2 * 64u + lane];
        unsigned int ub3 = hp[(unsigned)b3 * 64u + lane];
        ax0 = fmaf(e0, bflo(ua0), ax0); ay0 = fmaf(e0, bfhi(ua0), ay0);
        ax0 = fmaf(e1, bflo(ua1), ax0); ay0 = fmaf(e1, bfhi(ua1), ay0);
        ax0 = fmaf(e2, bflo(ua2), ax0); ay0 = fmaf(e2, bfhi(ua2), ay0);
        ax0 = fmaf(e3, bflo(ua3), ax0); ay0 = fmaf(e3, bfhi(ua3), ay0);
        ax1 = fmaf(f0, bflo(ub0), ax1); ay1 = fmaf(f0, bfhi(ub0), ay1);
        ax1 = fmaf(f1, bflo(ub1), ax1); ay1 = fmaf(f1, bfhi(ub1), ay1);
        ax1 = fmaf(f2, bflo(ub2), ax1); ay1 = fmaf(f2, bfhi(ub2), ay1);
        ax1 = fmaf(f3, bflo(ub3), ax1); ay1 = fmaf(f3, bfhi(ub3), ay1);
    }
    float ox0 = fmaxf(fmaf(dinv0, ax0, bgv.x), 0.f) + st0.x;
    float oy0 = fmaxf(fmaf(dinv0, ay0, bgv.y), 0.f) + st0.y;
    float ox1 = fmaxf(fmaf(dinv1, ax1, bgv.x), 0.f) + st1.x;
    float oy1 = fmaxf(fmaf(dinv1, ay1, bgv.y), 0.f) + st1.y;
    unsigned int p0 = ((unsigned int)(unsigned short)f2bf(oy0) << 16)
                    | ((unsigned int)(unsigned short)f2bf(ox0));
    unsigned int p1 = ((unsigned int)(unsigned short)f2bf(oy1) << 16)
                    | ((unsigned int)(unsigned short)f2bf(ox1));
    xb[(unsigned)row0 * 64u + lane] = p0;
    xb[(unsigned)row1 * 64u + lane] = p1;
}

// K3: MFMA MLP (R10 proven version).
__launch_bounds__(256)
__global__ void k_mlp(const unsigned int* __restrict__ xb,
                      const float* __restrict__ W1, const float* __restrict__ b1,
                      const float* __restrict__ W2, const float* __restrict__ b2,
                      const float* __restrict__ W3, const float* __restrict__ b3,
                      float* __restrict__ out, float* __restrict__ sum) {
    __shared__ __align__(16) short BsH[32 * 136];   // W1^T hi
    __shared__ __align__(16) short BsL[32 * 136];   // W1^T lo
    __shared__ float  zs[4][16 * 33];
    __shared__ float4 W2s[32 * 8];
    __shared__ float  b1s[32], b2s[32], W3s[32];
    __shared__ float  wred[4];
    const int t = threadIdx.x;

    for (int idx = t; idx < 128 * 32; idx += 256) {
        int k = idx >> 5, j = idx & 31;
        float f = W1[idx];
        short hi = f2bf(f);
        short lo = f2bf(f - bf2f(hi));
        BsH[j * 136 + k] = hi;
        BsL[j * 136 + k] = lo;
    }
    W2s[t] = ((const float4*)W2)[t];
    if (t < 32) { b1s[t] = b1[t]; b2s[t] = b2[t]; W3s[t] = W3[t]; }
    __syncthreads();

    const int wv = t >> 6, lane = t & 63;
    const int quad = lane >> 4, m = lane & 15;
    const int rbase = (blockIdx.x * 4 + wv) * 16;
    float wavesum = 0.f;

    if (rbase < N_NODES) {
        v8s a[4];
        const int4* xp = (const int4*)(xb + (size_t)(rbase + m) * 64);
#pragma unroll
        for (int q = 0; q < 4; ++q) a[q] = *(const v8s*)&xp[q * 4 + quad];

        v4f acc0 = (v4f)0.f, acc1 = (v4f)0.f;
#pragma unroll
        for (int q = 0; q < 4; ++q) {
            v8s bh0 = *(const v8s*)&BsH[m * 136 + q * 32 + quad * 8];
            v8s bh1 = *(const v8s*)&BsH[(16 + m) * 136 + q * 32 + quad * 8];
            acc0 = __builtin_amdgcn_mfma_f32_16x16x32_bf16(a[q], bh0, acc0, 0, 0, 0);
            acc1 = __builtin_amdgcn_mfma_f32_16x16x32_bf16(a[q], bh1, acc1, 0, 0, 0);
        }
#pragma unroll
        for (int q = 0; q < 4; ++q) {
            v8s bl0 = *(const v8s*)&BsL[m * 136 + q * 32 + quad * 8];
            v8s bl1 = *(const v8s*)&BsL[(16 + m) * 136 + q * 32 + quad * 8];
            acc0 = __builtin_amdgcn_mfma_f32_16x16x32_bf16(a[q], bl0, acc0, 0, 0, 0);
            acc1 = __builtin_amdgcn_mfma_f32_16x16x32_bf16(a[q], bl1, acc1, 0, 0, 0);
        }

        float* zsw = zs[wv];
        float bj0 = b1s[m], bj1 = b1s[16 + m];
#pragma unroll
        for (int r = 0; r < 4; ++r) {
            float h0 = acc0[r] + bj0; h0 = h0 > 0.f ? h0 : 0.01f * h0;
            float h1 = acc1[r] + bj1; h1 = h1 > 0.f ? h1 : 0.01f * h1;
            zsw[(quad * 4 + r) * 33 + m]      = h0;
            zsw[(quad * 4 + r) * 33 + 16 + m] = h1;
        }
        asm volatile("s_waitcnt lgkmcnt(0)" ::: "memory");

        float h2[8];
#pragma unroll
        for (int j = 0; j < 8; ++j) h2[j] = b2s[quad * 8 + j];
        const float* zrow = &zsw[m * 33];
#pragma unroll
        for (int k = 0; k < 32; ++k) {
            float zk = zrow[k];
            float4 wA = W2s[k * 8 + quad * 2];
            float4 wB = W2s[k * 8 + quad * 2 + 1];
            h2[0] = fmaf(zk, wA.x, h2[0]); h2[1] = fmaf(zk, wA.y, h2[1]);
            h2[2] = fmaf(zk, wA.z, h2[2]); h2[3] = fmaf(zk, wA.w, h2[3]);
            h2[4] = fmaf(zk, wB.x, h2[4]); h2[5] = fmaf(zk, wB.y, h2[5]);
            h2[6] = fmaf(zk, wB.z, h2[6]); h2[7] = fmaf(zk, wB.w, h2[7]);
        }
        float a3p = 0.f;
#pragma unroll
        for (int j = 0; j < 8; ++j) {
            float z2 = h2[j] > 0.f ? h2[j] : 0.01f * h2[j];
            a3p = fmaf(z2, W3s[quad * 8 + j], a3p);
        }
        a3p += __shfl_xor(a3p, 16, 64);
        a3p += __shfl_xor(a3p, 32, 64);
        float a3 = a3p + b3[0];
        float sp = fmaxf(a3, 0.f) + log1pf(expf(-fabsf(a3)));  // stable softplus
        if (quad == 0) out[rbase + m] = sp;
        float p = (quad == 0) ? sp : 0.f;
#pragma unroll
        for (int off = 32; off >= 1; off >>= 1) p += __shfl_xor(p, off, 64);
        wavesum = p;
    }
    if (lane == 0) wred[wv] = wavesum;
    __syncthreads();
    if (t == 0) atomicAdd(sum, (wred[0] + wred[1]) + (wred[2] + wred[3]));
}

// K4: in-place action = conc / (sum + 1e-20), float4-vectorized
__global__ void k_norm(const float* __restrict__ sum, float* __restrict__ out) {
    int i = blockIdx.x * blockDim.x + threadIdx.x;
    if (i < N_NODES / 4) {
        float inv = 1.0f / (*sum + 1e-20f);
        float4* o4 = (float4*)out;
        float4 v = o4[i];
        v.x *= inv; v.y *= inv; v.z *= inv; v.w *= inv;
        o4[i] = v;
    }
}

extern "C" void kernel_launch(void* const* d_in, const int* in_sizes, int n_in,
                              void* d_out, int out_size, void* d_ws, size_t ws_size,
                              hipStream_t stream) {
    const float* state = (const float*)d_in[0];
    const float* Wg    = (const float*)d_in[1];
    const float* bg    = (const float*)d_in[2];
    const float* W1    = (const float*)d_in[3];
    const float* b1    = (const float*)d_in[4];
    const float* W2    = (const float*)d_in[5];
    const float* b2    = (const float*)d_in[6];
    const float* W3    = (const float*)d_in[7];
    const float* b3    = (const float*)d_in[8];
    const int*   eidx  = (const int*)d_in[9];
    float* out = (float*)d_out;

    int*   wi = (int*)d_ws;
    float* wf = (float*)d_ws;
    int*   cnt    = wi + WS_CNT;
    float* sum    = wf + WS_SUM;
    unsigned short* bucket = (unsigned short*)(wi + WS_BUCKET);
    unsigned short* hs = (unsigned short*)(wf + WS_HS);
    unsigned int*   xb = (unsigned int*)(wf + WS_X);

    hipMemsetAsync(cnt, 0, 60001 * sizeof(int), stream);  // cnt + sum

    // fat: 938 gemm blocks (r7<2) + 2344 hist blocks (r7>=2) = 3282
    k_fat<<<3282, 256, 0, stream>>>(state, Wg, eidx, cnt, bucket, hs);
    // gather: 2 rows/wave interleaved, 4 waves/block -> 7500 blocks
    k_gather<<<(N_NODES + 7) / 8, 256, 0, stream>>>(hs, state, cnt, bucket, bg, xb);
    // mlp: 16 rows/wave, 4 waves/block -> 938 blocks
    k_mlp<<<938, 256, 0, stream>>>(xb, W1, b1, W2, b2, W3, b3, out, sum);
    k_norm<<<(N_NODES / 4 + 255) / 256, 256, 0, stream>>>(sum, out);
}